// Round 3
// baseline (616.911 us; speedup 1.0000x reference)
//
#include <hip/hip_runtime.h>

#define N_NODES 20000
#define N_PAD 20032            // 313 * 64
#define N_EDGES 320000
#define HIDDEN 256
#define N_GRAPHS 64
#define OUT_DIM 2

typedef __attribute__((ext_vector_type(8))) short short8v;
typedef __attribute__((ext_vector_type(4))) float f32x4;

// ---------------- int degree histogram ----------------
__global__ void k_degree(const int* __restrict__ dst, int* __restrict__ degi) {
    int e = blockIdx.x * blockDim.x + threadIdx.x;
    if (e < N_EDGES) atomicAdd(&degi[dst[e]], 1);
}

__global__ void k_dinv(const int* __restrict__ degi, float* __restrict__ dinv) {
    int i = blockIdx.x * blockDim.x + threadIdx.x;
    if (i < N_NODES) dinv[i] = rsqrtf((float)degi[i] + 1.0f); // +1 self-loop
}

// ---------------- exclusive scan of degrees -> rowptr (+mutable copy) ----------------
__global__ void k_scan(const int* __restrict__ degi, int* __restrict__ rowptr,
                       int* __restrict__ rowstart) {
    __shared__ int sums[1024];
    int t = threadIdx.x;
    int base = t * 20;
    int ld[20];
    int local = 0;
    if (t < 1000) {
#pragma unroll
        for (int i = 0; i < 20; ++i) { ld[i] = degi[base + i]; local += ld[i]; }
    }
    sums[t] = local;
    __syncthreads();
    for (int off = 1; off < 1024; off <<= 1) {
        int v = (t >= off) ? sums[t - off] : 0;
        __syncthreads();
        sums[t] += v;
        __syncthreads();
    }
    if (t < 1000) {
        int run = (t == 0) ? 0 : sums[t - 1];
#pragma unroll
        for (int i = 0; i < 20; ++i) {
            rowptr[base + i] = run;
            rowstart[base + i] = run;
            run += ld[i];
        }
    }
    if (t == 1023) rowptr[N_NODES] = sums[1023];
}

// ---------------- CSR fill ----------------
__global__ void k_fill(const int* __restrict__ src, const int* __restrict__ dst,
                       const float* __restrict__ dinv, int* __restrict__ rowstart,
                       int2* __restrict__ csr) {
    int e = blockIdx.x * blockDim.x + threadIdx.x;
    if (e >= N_EDGES) return;
    int s = src[e], d = dst[e];
    int pos = atomicAdd(&rowstart[d], 1);
    csr[pos] = make_int2(s, __float_as_int(dinv[s] * dinv[d]));
}

// ---------------- W -> transposed bf16 hi/lo split ----------------
__global__ void k_wprep(const float* __restrict__ W, ushort* __restrict__ wt_hi,
                        ushort* __restrict__ wt_lo) {
    int idx = blockIdx.x * blockDim.x + threadIdx.x; // 65536
    int k = idx & 255, n = idx >> 8;
    float a = W[k * 256 + n];
    unsigned u = __float_as_uint(a);
    ushort hi = (ushort)(u >> 16);
    float hif = __uint_as_float(u & 0xffff0000u);
    ushort lo = (ushort)(__float_as_uint(a - hif) >> 16);
    wt_hi[n * 256 + k] = hi;
    wt_lo[n * 256 + k] = lo;
}

// ---------------- layer 1 input GEMM (IN_DIM=3) ----------------
__global__ void k_lin1(const float* __restrict__ x, const float* __restrict__ W,
                       float* __restrict__ h) {
    int i = blockIdx.x;
    int j = threadIdx.x;
    float x0 = x[i * 3 + 0], x1 = x[i * 3 + 1], x2 = x[i * 3 + 2];
    h[i * HIDDEN + j] = x0 * W[j] + x1 * W[HIDDEN + j] + x2 * W[2 * HIDDEN + j];
}

// ---------------- MFMA split-bf16 GEMM: [N_PAD x 256] @ [256 x 256] ----------------
// block = 64 rows x 256 cols, 4 waves x 16 rows each. A frags direct from global,
// B frags from L2-hot transposed hi/lo tables. err ~2^-15 vs fp32.
template <bool RELU>
__global__ __launch_bounds__(256) void k_gemm_mfma(const float* __restrict__ in,
                                                   const ushort* __restrict__ wt_hi,
                                                   const ushort* __restrict__ wt_lo,
                                                   float* __restrict__ out) {
    int w = threadIdx.x >> 6;   // wave 0..3
    int l = threadIdx.x & 63;
    int lr = l & 15;            // row-in-frag (A) / col-in-frag (B, C)
    int kg = l >> 4;            // k-group 0..3
    int rowbase = blockIdx.x * 64 + w * 16;
    const float* arow = in + (size_t)(rowbase + lr) * HIDDEN + kg * 8;

    f32x4 acc[16];
#pragma unroll
    for (int c = 0; c < 16; ++c) acc[c] = (f32x4){0.f, 0.f, 0.f, 0.f};

    for (int t = 0; t < 8; ++t) {
        float4 v0 = *reinterpret_cast<const float4*>(arow + t * 32);
        float4 v1 = *reinterpret_cast<const float4*>(arow + t * 32 + 4);
        float av[8] = {v0.x, v0.y, v0.z, v0.w, v1.x, v1.y, v1.z, v1.w};
        short8v ah, al;
#pragma unroll
        for (int j = 0; j < 8; ++j) {
            float a = RELU ? fmaxf(av[j], 0.0f) : av[j];
            unsigned u = __float_as_uint(a);
            ah[j] = (short)(u >> 16);
            float hif = __uint_as_float(u & 0xffff0000u);
            al[j] = (short)(__float_as_uint(a - hif) >> 16);
        }
        const ushort* bbase_h = wt_hi + (size_t)lr * 256 + t * 32 + kg * 8;
        const ushort* bbase_l = wt_lo + (size_t)lr * 256 + t * 32 + kg * 8;
#pragma unroll
        for (int c = 0; c < 16; ++c) {
            short8v bh = *reinterpret_cast<const short8v*>(bbase_h + c * 16 * 256);
            short8v bl = *reinterpret_cast<const short8v*>(bbase_l + c * 16 * 256);
            acc[c] = __builtin_amdgcn_mfma_f32_16x16x32_bf16(ah, bh, acc[c], 0, 0, 0);
            acc[c] = __builtin_amdgcn_mfma_f32_16x16x32_bf16(ah, bl, acc[c], 0, 0, 0);
            acc[c] = __builtin_amdgcn_mfma_f32_16x16x32_bf16(al, bh, acc[c], 0, 0, 0);
        }
    }
    // C/D layout: col = lane&15, row = (lane>>4)*4 + reg   [m89-verified]
    float* orow = out + (size_t)(rowbase + kg * 4) * HIDDEN + lr;
#pragma unroll
    for (int r = 0; r < 4; ++r)
#pragma unroll
        for (int c = 0; c < 16; ++c)
            orow[(size_t)r * HIDDEN + c * 16] = acc[c][r];
}

// ---------------- gather aggregation: one wave per node ----------------
__global__ void k_csr_agg(const float* __restrict__ h, const float* __restrict__ dinv,
                          const int* __restrict__ rowptr, const int2* __restrict__ csr,
                          const float* __restrict__ b, float* __restrict__ out) {
    int node = blockIdx.x * 4 + (threadIdx.x >> 6);
    if (node >= N_NODES) return;
    int lane = threadIdx.x & 63;
    int beg = rowptr[node], end = rowptr[node + 1];
    float di = dinv[node];
    float w0 = di * di;
    float4 bv = *reinterpret_cast<const float4*>(b + lane * 4);
    float4 hv = *reinterpret_cast<const float4*>(h + (size_t)node * HIDDEN + lane * 4);
    float4 acc;
    acc.x = fmaf(hv.x, w0, bv.x);
    acc.y = fmaf(hv.y, w0, bv.y);
    acc.z = fmaf(hv.z, w0, bv.z);
    acc.w = fmaf(hv.w, w0, bv.w);
    for (int k = beg; k < end; ++k) {
        int2 ew = csr[k];
        float w = __int_as_float(ew.y);
        float4 v = *reinterpret_cast<const float4*>(h + (size_t)ew.x * HIDDEN + lane * 4);
        acc.x = fmaf(v.x, w, acc.x);
        acc.y = fmaf(v.y, w, acc.y);
        acc.z = fmaf(v.z, w, acc.z);
        acc.w = fmaf(v.w, w, acc.w);
    }
    *reinterpret_cast<float4*>(out + (size_t)node * HIDDEN + lane * 4) = acc;
}

// ---------------- pooling ----------------
__global__ void k_pool(const float* __restrict__ agg, const int* __restrict__ batch,
                       float* __restrict__ pooled) {
    int base = blockIdx.x * 32;
    int j = threadIdx.x;
    float acc = 0.0f;
    int cur = batch[base];
    for (int r = 0; r < 32; ++r) {
        int i = base + r;
        if (i >= N_NODES) break;
        int bg = batch[i];
        if (bg != cur) {
            atomicAdd(&pooled[cur * HIDDEN + j], acc);
            acc = 0.0f;
            cur = bg;
        }
        acc += fmaxf(agg[i * HIDDEN + j], 0.0f);
    }
    atomicAdd(&pooled[cur * HIDDEN + j], acc);
}

// ---------------- final linear ----------------
__global__ void k_final(const float* __restrict__ pooled, const float* __restrict__ Wlin,
                        const float* __restrict__ blin, float* __restrict__ out) {
    int t = threadIdx.x; // 0..127
    int g = t >> 1, o = t & 1;
    float s = blin[o];
    for (int k = 0; k < HIDDEN; ++k) s += pooled[g * HIDDEN + k] * Wlin[k * OUT_DIM + o];
    out[g * OUT_DIM + o] = s;
}

extern "C" void kernel_launch(void* const* d_in, const int* in_sizes, int n_in,
                              void* d_out, int out_size, void* d_ws, size_t ws_size,
                              hipStream_t stream) {
    const float* x     = (const float*)d_in[0];
    const int*   esrc  = (const int*)d_in[1];
    const int*   edst  = esrc + N_EDGES;
    const int*   batch = (const int*)d_in[2];
    const float* W1 = (const float*)d_in[3];
    const float* b1 = (const float*)d_in[4];
    const float* W2 = (const float*)d_in[5];
    const float* b2 = (const float*)d_in[6];
    const float* W3 = (const float*)d_in[7];
    const float* b3 = (const float*)d_in[8];
    const float* W4 = (const float*)d_in[9];
    const float* b4 = (const float*)d_in[10];
    const float* W5 = (const float*)d_in[11];
    const float* b5 = (const float*)d_in[12];
    const float* Wlin = (const float*)d_in[13];
    const float* blin = (const float*)d_in[14];
    float* out = (float*)d_out;

    char* ws = (char*)d_ws;
    size_t off = 0;
    auto alloc = [&](size_t bytes) { size_t o = off; off += (bytes + 255) & ~size_t(255); return (void*)(ws + o); };

    int*   degi     = (int*)alloc(N_NODES * 4);
    float* dinv     = (float*)alloc(N_NODES * 4);
    int*   rowptr   = (int*)alloc((N_NODES + 1) * 4);
    int*   rowstart = (int*)alloc(N_NODES * 4);
    int2*  csr      = (int2*)alloc((size_t)N_EDGES * 8);
    float* hA       = (float*)alloc((size_t)N_PAD * HIDDEN * 4);
    float* hB       = (float*)alloc((size_t)N_PAD * HIDDEN * 4);
    float* pooled   = (float*)alloc(N_GRAPHS * HIDDEN * 4);
    ushort* wt_hi   = (ushort*)alloc((size_t)4 * HIDDEN * HIDDEN * 2);
    ushort* wt_lo   = (ushort*)alloc((size_t)4 * HIDDEN * HIDDEN * 2);

    hipMemsetAsync(degi, 0, N_NODES * 4, stream);
    hipMemsetAsync(pooled, 0, N_GRAPHS * HIDDEN * 4, stream);

    k_degree<<<(N_EDGES + 255) / 256, 256, 0, stream>>>(edst, degi);
    k_dinv<<<(N_NODES + 255) / 256, 256, 0, stream>>>(degi, dinv);
    k_scan<<<1, 1024, 0, stream>>>(degi, rowptr, rowstart);
    k_fill<<<(N_EDGES + 255) / 256, 256, 0, stream>>>(esrc, edst, dinv, rowstart, csr);

    const float* Ws[5] = {W1, W2, W3, W4, W5};
    const float* bs[5] = {b1, b2, b3, b4, b5};
    for (int l = 1; l < 5; ++l)
        k_wprep<<<256, 256, 0, stream>>>(Ws[l], wt_hi + (size_t)(l - 1) * 65536,
                                         wt_lo + (size_t)(l - 1) * 65536);

    // layer 1
    k_lin1<<<N_NODES, HIDDEN, 0, stream>>>(x, W1, hA);
    k_csr_agg<<<N_NODES / 4, 256, 0, stream>>>(hA, dinv, rowptr, csr, b1, hB);

    // layers 2..5
    for (int l = 1; l < 5; ++l) {
        k_gemm_mfma<true><<<N_PAD / 64, 256, 0, stream>>>(
            hB, wt_hi + (size_t)(l - 1) * 65536, wt_lo + (size_t)(l - 1) * 65536, hA);
        k_csr_agg<<<N_NODES / 4, 256, 0, stream>>>(hA, dinv, rowptr, csr, bs[l], hB);
    }

    k_pool<<<N_NODES / 32, HIDDEN, 0, stream>>>(hB, batch, pooled);
    k_final<<<1, 128, 0, stream>>>(pooled, Wlin, blin, out);
}

// Round 4
// 566.675 us; speedup vs baseline: 1.0887x; 1.0887x over previous
//
#include <hip/hip_runtime.h>

#define N_NODES 20000
#define N_PAD 20032            // 626 * 32
#define N_EDGES 320000
#define HIDDEN 256
#define N_GRAPHS 64
#define OUT_DIM 2

typedef __attribute__((ext_vector_type(8))) short short8v;
typedef __attribute__((ext_vector_type(4))) float f32x4;
typedef __attribute__((ext_vector_type(4))) unsigned short us4;

// ---------------- int degree histogram ----------------
__global__ void k_degree(const int* __restrict__ dst, int* __restrict__ degi) {
    int e = blockIdx.x * blockDim.x + threadIdx.x;
    if (e < N_EDGES) atomicAdd(&degi[dst[e]], 1);
}

__global__ void k_dinv(const int* __restrict__ degi, float* __restrict__ dinv) {
    int i = blockIdx.x * blockDim.x + threadIdx.x;
    if (i < N_NODES) dinv[i] = rsqrtf((float)degi[i] + 1.0f); // +1 self-loop
}

// ---------------- exclusive scan of degrees -> rowptr (+mutable copy) ----------------
__global__ void k_scan(const int* __restrict__ degi, int* __restrict__ rowptr,
                       int* __restrict__ rowstart) {
    __shared__ int sums[1024];
    int t = threadIdx.x;
    int base = t * 20;
    int ld[20];
    int local = 0;
    if (t < 1000) {
#pragma unroll
        for (int i = 0; i < 20; ++i) { ld[i] = degi[base + i]; local += ld[i]; }
    }
    sums[t] = local;
    __syncthreads();
    for (int off = 1; off < 1024; off <<= 1) {
        int v = (t >= off) ? sums[t - off] : 0;
        __syncthreads();
        sums[t] += v;
        __syncthreads();
    }
    if (t < 1000) {
        int run = (t == 0) ? 0 : sums[t - 1];
#pragma unroll
        for (int i = 0; i < 20; ++i) {
            rowptr[base + i] = run;
            rowstart[base + i] = run;
            run += ld[i];
        }
    }
    if (t == 1023) rowptr[N_NODES] = sums[1023];
}

// ---------------- CSR fill ----------------
__global__ void k_fill(const int* __restrict__ src, const int* __restrict__ dst,
                       const float* __restrict__ dinv, int* __restrict__ rowstart,
                       int2* __restrict__ csr) {
    int e = blockIdx.x * blockDim.x + threadIdx.x;
    if (e >= N_EDGES) return;
    int s = src[e], d = dst[e];
    int pos = atomicAdd(&rowstart[d], 1);
    csr[pos] = make_int2(s, __float_as_int(dinv[s] * dinv[d]));
}

// ---------------- W2..W5 -> transposed bf16 hi/lo split (one launch) ----------------
__global__ void k_wprep4(const float* __restrict__ W2, const float* __restrict__ W3,
                         const float* __restrict__ W4, const float* __restrict__ W5,
                         ushort* __restrict__ wt_hi, ushort* __restrict__ wt_lo) {
    int lid = blockIdx.x >> 8;                       // 0..3
    int idx = (blockIdx.x & 255) * 256 + threadIdx.x;
    const float* W = lid == 0 ? W2 : lid == 1 ? W3 : lid == 2 ? W4 : W5;
    int k = idx & 255, n = idx >> 8;
    float a = W[k * 256 + n];
    unsigned u = __float_as_uint(a);
    ushort hi = (ushort)(u >> 16);
    float hif = __uint_as_float(u & 0xffff0000u);
    ushort lo = (ushort)(__float_as_uint(a - hif) >> 16);
    wt_hi[(size_t)lid * 65536 + n * 256 + k] = hi;
    wt_lo[(size_t)lid * 65536 + n * 256 + k] = lo;
}

// ---------------- layer 1 input GEMM (IN_DIM=3) ----------------
__global__ void k_lin1(const float* __restrict__ x, const float* __restrict__ W,
                       float* __restrict__ h) {
    int i = blockIdx.x;
    int j = threadIdx.x;
    float x0 = x[i * 3 + 0], x1 = x[i * 3 + 1], x2 = x[i * 3 + 2];
    h[i * HIDDEN + j] = x0 * W[j] + x1 * W[HIDDEN + j] + x2 * W[2 * HIDDEN + j];
}

// ---------------- gather aggregation, fused relu + bf16 hi/lo split epilogue ----------------
__global__ void k_csr_agg(const float* __restrict__ h, const float* __restrict__ dinv,
                          const int* __restrict__ rowptr, const int2* __restrict__ csr,
                          const float* __restrict__ b,
                          ushort* __restrict__ out_hi, ushort* __restrict__ out_lo) {
    int node = blockIdx.x * 4 + (threadIdx.x >> 6);
    if (node >= N_NODES) return;
    int lane = threadIdx.x & 63;
    int beg = rowptr[node], end = rowptr[node + 1];
    float di = dinv[node];
    float w0 = di * di;
    float4 bv = *reinterpret_cast<const float4*>(b + lane * 4);
    float4 hv = *reinterpret_cast<const float4*>(h + (size_t)node * HIDDEN + lane * 4);
    float4 acc;
    acc.x = fmaf(hv.x, w0, bv.x);
    acc.y = fmaf(hv.y, w0, bv.y);
    acc.z = fmaf(hv.z, w0, bv.z);
    acc.w = fmaf(hv.w, w0, bv.w);
    for (int k = beg; k < end; ++k) {
        int2 ew = csr[k];
        float w = __int_as_float(ew.y);
        float4 v = *reinterpret_cast<const float4*>(h + (size_t)ew.x * HIDDEN + lane * 4);
        acc.x = fmaf(v.x, w, acc.x);
        acc.y = fmaf(v.y, w, acc.y);
        acc.z = fmaf(v.z, w, acc.z);
        acc.w = fmaf(v.w, w, acc.w);
    }
    float rv[4] = {fmaxf(acc.x, 0.f), fmaxf(acc.y, 0.f), fmaxf(acc.z, 0.f), fmaxf(acc.w, 0.f)};
    us4 hvv, lvv;
#pragma unroll
    for (int j = 0; j < 4; ++j) {
        unsigned u = __float_as_uint(rv[j]);
        hvv[j] = (ushort)(u >> 16);
        float hif = __uint_as_float(u & 0xffff0000u);
        lvv[j] = (ushort)(__float_as_uint(rv[j] - hif) >> 16);
    }
    *reinterpret_cast<us4*>(out_hi + (size_t)node * HIDDEN + lane * 4) = hvv;
    *reinterpret_cast<us4*>(out_lo + (size_t)node * HIDDEN + lane * 4) = lvv;
}

// ---------------- MFMA split-bf16 GEMM: [N_PAD x 256] @ [256 x 256] ----------------
// block = 32 rows x 256 cols, 8 waves: wave (rg, cs) -> rows rg*16, cols cs*64.
// A pre-split bf16 hi/lo (relu'd in agg). err ~2^-15 vs fp32.
__global__ __launch_bounds__(512) void k_gemm_mfma(const ushort* __restrict__ a_hi,
                                                   const ushort* __restrict__ a_lo,
                                                   const ushort* __restrict__ wt_hi,
                                                   const ushort* __restrict__ wt_lo,
                                                   float* __restrict__ out) {
    int w = threadIdx.x >> 6;
    int l = threadIdx.x & 63;
    int lr = l & 15, kg = l >> 4;
    int row0 = blockIdx.x * 32 + (w >> 2) * 16;
    int col0 = (w & 3) * 64;
    const ushort* ap_h = a_hi + (size_t)(row0 + lr) * 256 + kg * 8;
    const ushort* ap_l = a_lo + (size_t)(row0 + lr) * 256 + kg * 8;
    const ushort* bp_h = wt_hi + (size_t)(col0 + lr) * 256 + kg * 8;
    const ushort* bp_l = wt_lo + (size_t)(col0 + lr) * 256 + kg * 8;

    f32x4 acc[4] = {};
#pragma unroll
    for (int t = 0; t < 8; ++t) {
        short8v ah = *reinterpret_cast<const short8v*>(ap_h + t * 32);
        short8v al = *reinterpret_cast<const short8v*>(ap_l + t * 32);
#pragma unroll
        for (int c = 0; c < 4; ++c) {
            short8v bh = *reinterpret_cast<const short8v*>(bp_h + c * 4096 + t * 32);
            short8v bl = *reinterpret_cast<const short8v*>(bp_l + c * 4096 + t * 32);
            acc[c] = __builtin_amdgcn_mfma_f32_16x16x32_bf16(ah, bh, acc[c], 0, 0, 0);
            acc[c] = __builtin_amdgcn_mfma_f32_16x16x32_bf16(ah, bl, acc[c], 0, 0, 0);
            acc[c] = __builtin_amdgcn_mfma_f32_16x16x32_bf16(al, bh, acc[c], 0, 0, 0);
        }
    }
    // C/D layout: col = lane&15, row = (lane>>4)*4 + reg   [m89-verified]
    float* orow = out + (size_t)(row0 + kg * 4) * 256 + col0 + lr;
#pragma unroll
    for (int r = 0; r < 4; ++r)
#pragma unroll
        for (int c = 0; c < 4; ++c)
            orow[(size_t)r * 256 + c * 16] = acc[c][r];
}

// ---------------- pooling from hi/lo (already relu'd) ----------------
__global__ void k_pool(const ushort* __restrict__ hi, const ushort* __restrict__ lo,
                       const int* __restrict__ batch, float* __restrict__ pooled) {
    int base = blockIdx.x * 32;
    int j = threadIdx.x;
    float acc = 0.0f;
    int cur = batch[base];
    for (int r = 0; r < 32; ++r) {
        int i = base + r;
        int bg = batch[i];
        if (bg != cur) {
            atomicAdd(&pooled[cur * HIDDEN + j], acc);
            acc = 0.0f;
            cur = bg;
        }
        size_t off = (size_t)i * HIDDEN + j;
        float v = __uint_as_float((unsigned)hi[off] << 16) +
                  __uint_as_float((unsigned)lo[off] << 16);
        acc += v;
    }
    atomicAdd(&pooled[cur * HIDDEN + j], acc);
}

// ---------------- final linear ----------------
__global__ void k_final(const float* __restrict__ pooled, const float* __restrict__ Wlin,
                        const float* __restrict__ blin, float* __restrict__ out) {
    int t = threadIdx.x; // 0..127
    int g = t >> 1, o = t & 1;
    float s = blin[o];
    for (int k = 0; k < HIDDEN; ++k) s += pooled[g * HIDDEN + k] * Wlin[k * OUT_DIM + o];
    out[g * OUT_DIM + o] = s;
}

extern "C" void kernel_launch(void* const* d_in, const int* in_sizes, int n_in,
                              void* d_out, int out_size, void* d_ws, size_t ws_size,
                              hipStream_t stream) {
    const float* x     = (const float*)d_in[0];
    const int*   esrc  = (const int*)d_in[1];
    const int*   edst  = esrc + N_EDGES;
    const int*   batch = (const int*)d_in[2];
    const float* W1 = (const float*)d_in[3];
    const float* b1 = (const float*)d_in[4];
    const float* W2 = (const float*)d_in[5];
    const float* b2 = (const float*)d_in[6];
    const float* W3 = (const float*)d_in[7];
    const float* b3 = (const float*)d_in[8];
    const float* W4 = (const float*)d_in[9];
    const float* b4 = (const float*)d_in[10];
    const float* W5 = (const float*)d_in[11];
    const float* b5 = (const float*)d_in[12];
    const float* Wlin = (const float*)d_in[13];
    const float* blin = (const float*)d_in[14];
    float* out = (float*)d_out;

    char* ws = (char*)d_ws;
    size_t off = 0;
    auto alloc = [&](size_t bytes) { size_t o = off; off += (bytes + 255) & ~size_t(255); return (void*)(ws + o); };

    int*    degi     = (int*)alloc(N_NODES * 4);
    float*  dinv     = (float*)alloc(N_NODES * 4);
    int*    rowptr   = (int*)alloc((N_NODES + 1) * 4);
    int*    rowstart = (int*)alloc(N_NODES * 4);
    int2*   csr      = (int2*)alloc((size_t)N_EDGES * 8);
    float*  hA       = (float*)alloc((size_t)N_PAD * HIDDEN * 4);
    ushort* hb_hi    = (ushort*)alloc((size_t)N_PAD * HIDDEN * 2);
    ushort* hb_lo    = (ushort*)alloc((size_t)N_PAD * HIDDEN * 2);
    float*  pooled   = (float*)alloc(N_GRAPHS * HIDDEN * 4);
    ushort* wt_hi    = (ushort*)alloc((size_t)4 * HIDDEN * HIDDEN * 2);
    ushort* wt_lo    = (ushort*)alloc((size_t)4 * HIDDEN * HIDDEN * 2);

    hipMemsetAsync(degi, 0, N_NODES * 4, stream);
    hipMemsetAsync(pooled, 0, N_GRAPHS * HIDDEN * 4, stream);

    k_degree<<<(N_EDGES + 255) / 256, 256, 0, stream>>>(edst, degi);
    k_dinv<<<(N_NODES + 255) / 256, 256, 0, stream>>>(degi, dinv);
    k_scan<<<1, 1024, 0, stream>>>(degi, rowptr, rowstart);
    k_fill<<<(N_EDGES + 255) / 256, 256, 0, stream>>>(esrc, edst, dinv, rowstart, csr);
    k_wprep4<<<1024, 256, 0, stream>>>(W2, W3, W4, W5, wt_hi, wt_lo);

    const float* bs[5] = {b1, b2, b3, b4, b5};

    // layer 1
    k_lin1<<<N_NODES, HIDDEN, 0, stream>>>(x, W1, hA);
    k_csr_agg<<<N_NODES / 4, 256, 0, stream>>>(hA, dinv, rowptr, csr, b1, hb_hi, hb_lo);

    // layers 2..5
    for (int l = 1; l < 5; ++l) {
        k_gemm_mfma<<<N_PAD / 32, 512, 0, stream>>>(
            hb_hi, hb_lo, wt_hi + (size_t)(l - 1) * 65536, wt_lo + (size_t)(l - 1) * 65536, hA);
        k_csr_agg<<<N_NODES / 4, 256, 0, stream>>>(hA, dinv, rowptr, csr, bs[l], hb_hi, hb_lo);
    }

    k_pool<<<N_NODES / 32, HIDDEN, 0, stream>>>(hb_hi, hb_lo, batch, pooled);
    k_final<<<1, 128, 0, stream>>>(pooled, Wlin, blin, out);
}

// Round 5
// 435.125 us; speedup vs baseline: 1.4178x; 1.3023x over previous
//
#include <hip/hip_runtime.h>

#define N_NODES 20000
#define N_PAD 20032            // 313 * 64
#define N_EDGES 320000
#define HIDDEN 256
#define N_GRAPHS 64
#define OUT_DIM 2

#define PANEL_BYTES 131072     // one N-half: hi(64KB) + lo(64KB), swizzled
#define TABLE_BYTES 65536

typedef __attribute__((ext_vector_type(8))) short short8v;
typedef __attribute__((ext_vector_type(4))) float f32x4;
typedef __attribute__((ext_vector_type(4))) unsigned short us4;

// ---------------- int degree histogram ----------------
__global__ void k_degree(const int* __restrict__ dst, int* __restrict__ degi) {
    int e = blockIdx.x * blockDim.x + threadIdx.x;
    if (e < N_EDGES) atomicAdd(&degi[dst[e]], 1);
}

__global__ void k_dinv(const int* __restrict__ degi, float* __restrict__ dinv) {
    int i = blockIdx.x * blockDim.x + threadIdx.x;
    if (i < N_NODES) dinv[i] = rsqrtf((float)degi[i] + 1.0f); // +1 self-loop
}

// ---------------- exclusive scan of degrees -> rowptr (+mutable copy) ----------------
__global__ void k_scan(const int* __restrict__ degi, int* __restrict__ rowptr,
                       int* __restrict__ rowstart) {
    __shared__ int sums[1024];
    int t = threadIdx.x;
    int base = t * 20;
    int ld[20];
    int local = 0;
    if (t < 1000) {
#pragma unroll
        for (int i = 0; i < 20; ++i) { ld[i] = degi[base + i]; local += ld[i]; }
    }
    sums[t] = local;
    __syncthreads();
    for (int off = 1; off < 1024; off <<= 1) {
        int v = (t >= off) ? sums[t - off] : 0;
        __syncthreads();
        sums[t] += v;
        __syncthreads();
    }
    if (t < 1000) {
        int run = (t == 0) ? 0 : sums[t - 1];
#pragma unroll
        for (int i = 0; i < 20; ++i) {
            rowptr[base + i] = run;
            rowstart[base + i] = run;
            run += ld[i];
        }
    }
    if (t == 1023) rowptr[N_NODES] = sums[1023];
}

// ---------------- CSR fill ----------------
__global__ void k_fill(const int* __restrict__ src, const int* __restrict__ dst,
                       const float* __restrict__ dinv, int* __restrict__ rowstart,
                       int2* __restrict__ csr) {
    int e = blockIdx.x * blockDim.x + threadIdx.x;
    if (e >= N_EDGES) return;
    int s = src[e], d = dst[e];
    int pos = atomicAdd(&rowstart[d], 1);
    csr[pos] = make_int2(s, __float_as_int(dinv[s] * dinv[d]));
}

// ---------------- W2..W5 -> swizzled LDS-image panels ----------------
// layout: per (layer, half): [hi table 64KB][lo table 64KB]
// within table: slab = k>>3 (2048 B each), chunk byte = (col*16 + slab*32) & 2047,
// element byte = + (k&7)*2.  The slab*32 rotation spreads kg-groups across banks.
__global__ void k_wprep4(const float* __restrict__ W2, const float* __restrict__ W3,
                         const float* __restrict__ W4, const float* __restrict__ W5,
                         char* __restrict__ wt) {
    int lid = blockIdx.x >> 8;                       // 0..3
    int idx = (blockIdx.x & 255) * 256 + threadIdx.x;
    const float* W = lid == 0 ? W2 : lid == 1 ? W3 : lid == 2 ? W4 : W5;
    int k = idx & 255, n = idx >> 8;
    float a = W[k * 256 + n];
    unsigned u = __float_as_uint(a);
    ushort hi = (ushort)(u >> 16);
    float hif = __uint_as_float(u & 0xffff0000u);
    ushort lo = (ushort)(__float_as_uint(a - hif) >> 16);
    int half = n >> 7, colL = n & 127, slab = k >> 3, e = k & 7;
    size_t base = ((size_t)lid * 2 + half) * PANEL_BYTES;
    size_t soff = (size_t)slab * 2048 + ((colL * 16 + slab * 32) & 2047) + e * 2;
    *(ushort*)(wt + base + soff) = hi;
    *(ushort*)(wt + base + TABLE_BYTES + soff) = lo;
}

// ---------------- layer 1 input GEMM (IN_DIM=3) ----------------
__global__ void k_lin1(const float* __restrict__ x, const float* __restrict__ W,
                       float* __restrict__ h) {
    int i = blockIdx.x;
    int j = threadIdx.x;
    float x0 = x[i * 3 + 0], x1 = x[i * 3 + 1], x2 = x[i * 3 + 2];
    h[i * HIDDEN + j] = x0 * W[j] + x1 * W[HIDDEN + j] + x2 * W[2 * HIDDEN + j];
}

// ---------------- gather aggregation, fused relu + bf16 hi/lo split epilogue ----------------
__global__ void k_csr_agg(const float* __restrict__ h, const float* __restrict__ dinv,
                          const int* __restrict__ rowptr, const int2* __restrict__ csr,
                          const float* __restrict__ b,
                          ushort* __restrict__ out_hi, ushort* __restrict__ out_lo) {
    int node = blockIdx.x * 4 + (threadIdx.x >> 6);
    if (node >= N_NODES) return;
    int lane = threadIdx.x & 63;
    int beg = rowptr[node], end = rowptr[node + 1];
    float di = dinv[node];
    float w0 = di * di;
    float4 bv = *reinterpret_cast<const float4*>(b + lane * 4);
    float4 hv = *reinterpret_cast<const float4*>(h + (size_t)node * HIDDEN + lane * 4);
    float4 acc, acc2 = {0.f, 0.f, 0.f, 0.f};
    acc.x = fmaf(hv.x, w0, bv.x);
    acc.y = fmaf(hv.y, w0, bv.y);
    acc.z = fmaf(hv.z, w0, bv.z);
    acc.w = fmaf(hv.w, w0, bv.w);
    int k = beg;
    for (; k + 1 < end; k += 2) {
        int2 e0 = csr[k], e1 = csr[k + 1];
        float we0 = __int_as_float(e0.y), we1 = __int_as_float(e1.y);
        float4 v0 = *reinterpret_cast<const float4*>(h + (size_t)e0.x * HIDDEN + lane * 4);
        float4 v1 = *reinterpret_cast<const float4*>(h + (size_t)e1.x * HIDDEN + lane * 4);
        acc.x = fmaf(v0.x, we0, acc.x);   acc2.x = fmaf(v1.x, we1, acc2.x);
        acc.y = fmaf(v0.y, we0, acc.y);   acc2.y = fmaf(v1.y, we1, acc2.y);
        acc.z = fmaf(v0.z, we0, acc.z);   acc2.z = fmaf(v1.z, we1, acc2.z);
        acc.w = fmaf(v0.w, we0, acc.w);   acc2.w = fmaf(v1.w, we1, acc2.w);
    }
    if (k < end) {
        int2 e0 = csr[k];
        float we0 = __int_as_float(e0.y);
        float4 v0 = *reinterpret_cast<const float4*>(h + (size_t)e0.x * HIDDEN + lane * 4);
        acc.x = fmaf(v0.x, we0, acc.x);
        acc.y = fmaf(v0.y, we0, acc.y);
        acc.z = fmaf(v0.z, we0, acc.z);
        acc.w = fmaf(v0.w, we0, acc.w);
    }
    acc.x += acc2.x; acc.y += acc2.y; acc.z += acc2.z; acc.w += acc2.w;
    float rv[4] = {fmaxf(acc.x, 0.f), fmaxf(acc.y, 0.f), fmaxf(acc.z, 0.f), fmaxf(acc.w, 0.f)};
    us4 hvv, lvv;
#pragma unroll
    for (int j = 0; j < 4; ++j) {
        unsigned u = __float_as_uint(rv[j]);
        hvv[j] = (ushort)(u >> 16);
        float hif = __uint_as_float(u & 0xffff0000u);
        lvv[j] = (ushort)(__float_as_uint(rv[j] - hif) >> 16);
    }
    *reinterpret_cast<us4*>(out_hi + (size_t)node * HIDDEN + lane * 4) = hvv;
    *reinterpret_cast<us4*>(out_lo + (size_t)node * HIDDEN + lane * 4) = lvv;
}

// ---------------- MFMA split-bf16 GEMM with LDS-staged B panel ----------------
// block = 64 rows x 128 cols (one N-half). 8 waves = 2M x 4N, wave = 32r x 32c.
// B (hi+lo, 128 KiB) staged once into LDS; K-loop has no barriers.
__global__ __launch_bounds__(512) void k_gemm_mfma(const ushort* __restrict__ a_hi,
                                                   const ushort* __restrict__ a_lo,
                                                   const char* __restrict__ wpanels,
                                                   float* __restrict__ out) {
    extern __shared__ char smem[];
    int bx = blockIdx.x;
    int half = bx & 1;
    int mtile = bx >> 1;
    const char* gsrc = wpanels + (size_t)half * PANEL_BYTES;
    int tid = threadIdx.x;
#pragma unroll
    for (int it = 0; it < 16; ++it) {
        int o = it * 8192 + tid * 16;
        *reinterpret_cast<float4*>(smem + o) = *reinterpret_cast<const float4*>(gsrc + o);
    }
    __syncthreads();

    int w = tid >> 6, l = tid & 63;
    int lr = l & 15, kg = l >> 4;
    int wm = w >> 2, wn = w & 3;          // 2M x 4N
    int row0 = mtile * 64 + wm * 32;
    int colL0 = wn * 32;

    const ushort* aph = a_hi + (size_t)(row0 + lr) * HIDDEN + kg * 8;
    const ushort* apl = a_lo + (size_t)(row0 + lr) * HIDDEN + kg * 8;

    f32x4 acc[2][2] = {};
#pragma unroll
    for (int t = 0; t < 8; ++t) {
        int kb = t * 32;
        short8v ah0 = *reinterpret_cast<const short8v*>(aph + kb);
        short8v ah1 = *reinterpret_cast<const short8v*>(aph + 16 * HIDDEN + kb);
        short8v al0 = *reinterpret_cast<const short8v*>(apl + kb);
        short8v al1 = *reinterpret_cast<const short8v*>(apl + 16 * HIDDEN + kb);
        int slab = t * 4 + kg;
        int sbase = slab * 2048;
        int rot = slab * 32;
#pragma unroll
        for (int cf = 0; cf < 2; ++cf) {
            int colL = colL0 + cf * 16 + lr;
            int off = sbase + ((colL * 16 + rot) & 2047);
            short8v bh = *reinterpret_cast<const short8v*>(smem + off);
            short8v bl = *reinterpret_cast<const short8v*>(smem + TABLE_BYTES + off);
            acc[0][cf] = __builtin_amdgcn_mfma_f32_16x16x32_bf16(ah0, bh, acc[0][cf], 0, 0, 0);
            acc[1][cf] = __builtin_amdgcn_mfma_f32_16x16x32_bf16(ah1, bh, acc[1][cf], 0, 0, 0);
            acc[0][cf] = __builtin_amdgcn_mfma_f32_16x16x32_bf16(al0, bh, acc[0][cf], 0, 0, 0);
            acc[1][cf] = __builtin_amdgcn_mfma_f32_16x16x32_bf16(al1, bh, acc[1][cf], 0, 0, 0);
            acc[0][cf] = __builtin_amdgcn_mfma_f32_16x16x32_bf16(ah0, bl, acc[0][cf], 0, 0, 0);
            acc[1][cf] = __builtin_amdgcn_mfma_f32_16x16x32_bf16(ah1, bl, acc[1][cf], 0, 0, 0);
        }
    }
    // C/D layout: col = lane&15, row = (lane>>4)*4 + reg   [m89-verified]
    int gcol = half * 128 + colL0 + lr;
#pragma unroll
    for (int rf = 0; rf < 2; ++rf) {
        float* orow = out + (size_t)(row0 + rf * 16 + kg * 4) * HIDDEN + gcol;
#pragma unroll
        for (int r = 0; r < 4; ++r)
#pragma unroll
            for (int cf = 0; cf < 2; ++cf)
                orow[(size_t)r * HIDDEN + cf * 16] = acc[rf][cf][r];
    }
}

// ---------------- pooling from hi/lo (already relu'd) ----------------
__global__ void k_pool(const ushort* __restrict__ hi, const ushort* __restrict__ lo,
                       const int* __restrict__ batch, float* __restrict__ pooled) {
    int base = blockIdx.x * 32;
    int j = threadIdx.x;
    float acc = 0.0f;
    int cur = batch[base];
    for (int r = 0; r < 32; ++r) {
        int i = base + r;
        int bg = batch[i];
        if (bg != cur) {
            atomicAdd(&pooled[cur * HIDDEN + j], acc);
            acc = 0.0f;
            cur = bg;
        }
        size_t off = (size_t)i * HIDDEN + j;
        float v = __uint_as_float((unsigned)hi[off] << 16) +
                  __uint_as_float((unsigned)lo[off] << 16);
        acc += v;
    }
    atomicAdd(&pooled[cur * HIDDEN + j], acc);
}

// ---------------- final linear ----------------
__global__ void k_final(const float* __restrict__ pooled, const float* __restrict__ Wlin,
                        const float* __restrict__ blin, float* __restrict__ out) {
    int t = threadIdx.x; // 0..127
    int g = t >> 1, o = t & 1;
    float s = blin[o];
    for (int k = 0; k < HIDDEN; ++k) s += pooled[g * HIDDEN + k] * Wlin[k * OUT_DIM + o];
    out[g * OUT_DIM + o] = s;
}

extern "C" void kernel_launch(void* const* d_in, const int* in_sizes, int n_in,
                              void* d_out, int out_size, void* d_ws, size_t ws_size,
                              hipStream_t stream) {
    const float* x     = (const float*)d_in[0];
    const int*   esrc  = (const int*)d_in[1];
    const int*   edst  = esrc + N_EDGES;
    const int*   batch = (const int*)d_in[2];
    const float* W1 = (const float*)d_in[3];
    const float* b1 = (const float*)d_in[4];
    const float* W2 = (const float*)d_in[5];
    const float* b2 = (const float*)d_in[6];
    const float* W3 = (const float*)d_in[7];
    const float* b3 = (const float*)d_in[8];
    const float* W4 = (const float*)d_in[9];
    const float* b4 = (const float*)d_in[10];
    const float* W5 = (const float*)d_in[11];
    const float* b5 = (const float*)d_in[12];
    const float* Wlin = (const float*)d_in[13];
    const float* blin = (const float*)d_in[14];
    float* out = (float*)d_out;

    char* ws = (char*)d_ws;
    size_t off = 0;
    auto alloc = [&](size_t bytes) { size_t o = off; off += (bytes + 255) & ~size_t(255); return (void*)(ws + o); };

    int*    degi     = (int*)alloc(N_NODES * 4);
    float*  dinv     = (float*)alloc(N_NODES * 4);
    int*    rowptr   = (int*)alloc((N_NODES + 1) * 4);
    int*    rowstart = (int*)alloc(N_NODES * 4);
    int2*   csr      = (int2*)alloc((size_t)N_EDGES * 8);
    float*  hA       = (float*)alloc((size_t)N_PAD * HIDDEN * 4);
    ushort* hb_hi    = (ushort*)alloc((size_t)N_PAD * HIDDEN * 2);
    ushort* hb_lo    = (ushort*)alloc((size_t)N_PAD * HIDDEN * 2);
    float*  pooled   = (float*)alloc(N_GRAPHS * HIDDEN * 4);
    char*   wt       = (char*)alloc((size_t)4 * 2 * PANEL_BYTES);

    hipMemsetAsync(degi, 0, N_NODES * 4, stream);
    hipMemsetAsync(pooled, 0, N_GRAPHS * HIDDEN * 4, stream);

    k_degree<<<(N_EDGES + 255) / 256, 256, 0, stream>>>(edst, degi);
    k_dinv<<<(N_NODES + 255) / 256, 256, 0, stream>>>(degi, dinv);
    k_scan<<<1, 1024, 0, stream>>>(degi, rowptr, rowstart);
    k_fill<<<(N_EDGES + 255) / 256, 256, 0, stream>>>(esrc, edst, dinv, rowstart, csr);
    k_wprep4<<<1024, 256, 0, stream>>>(W2, W3, W4, W5, wt);

    const float* bs[5] = {b1, b2, b3, b4, b5};

    // layer 1
    k_lin1<<<N_NODES, HIDDEN, 0, stream>>>(x, W1, hA);
    k_csr_agg<<<N_NODES / 4, 256, 0, stream>>>(hA, dinv, rowptr, csr, b1, hb_hi, hb_lo);

    // layers 2..5
    for (int l = 1; l < 5; ++l) {
        k_gemm_mfma<<<(N_PAD / 64) * 2, 512, PANEL_BYTES, stream>>>(
            hb_hi, hb_lo, wt + (size_t)(l - 1) * 2 * PANEL_BYTES, hA);
        k_csr_agg<<<N_NODES / 4, 256, 0, stream>>>(hA, dinv, rowptr, csr, bs[l], hb_hi, hb_lo);
    }

    k_pool<<<N_NODES / 32, HIDDEN, 0, stream>>>(hb_hi, hb_lo, batch, pooled);
    k_final<<<1, 128, 0, stream>>>(pooled, Wlin, blin, out);
}

// Round 6
// 399.097 us; speedup vs baseline: 1.5458x; 1.0903x over previous
//
#include <hip/hip_runtime.h>

#define N_NODES 20000
#define N_PAD 20032            // 313 * 64
#define N_EDGES 320000
#define HIDDEN 256
#define N_GRAPHS 64
#define OUT_DIM 2

#define PANEL_BYTES 131072     // one N-half: hi(64KB) + lo(64KB), swizzled
#define TABLE_BYTES 65536

typedef __attribute__((ext_vector_type(8))) short short8v;
typedef __attribute__((ext_vector_type(4))) float f32x4;
typedef __attribute__((ext_vector_type(4))) unsigned short us4;

// ---------------- int degree histogram ----------------
__global__ void k_degree(const int* __restrict__ dst, int* __restrict__ degi) {
    int e = blockIdx.x * blockDim.x + threadIdx.x;
    if (e < N_EDGES) atomicAdd(&degi[dst[e]], 1);
}

__global__ void k_dinv(const int* __restrict__ degi, float* __restrict__ dinv) {
    int i = blockIdx.x * blockDim.x + threadIdx.x;
    if (i < N_NODES) dinv[i] = rsqrtf((float)degi[i] + 1.0f); // +1 self-loop
}

// ---------------- exclusive scan of degrees -> rowptr (+mutable copy) ----------------
__global__ void k_scan(const int* __restrict__ degi, int* __restrict__ rowptr,
                       int* __restrict__ rowstart) {
    __shared__ int sums[1024];
    int t = threadIdx.x;
    int base = t * 20;
    int ld[20];
    int local = 0;
    if (t < 1000) {
#pragma unroll
        for (int i = 0; i < 20; ++i) { ld[i] = degi[base + i]; local += ld[i]; }
    }
    sums[t] = local;
    __syncthreads();
    for (int off = 1; off < 1024; off <<= 1) {
        int v = (t >= off) ? sums[t - off] : 0;
        __syncthreads();
        sums[t] += v;
        __syncthreads();
    }
    if (t < 1000) {
        int run = (t == 0) ? 0 : sums[t - 1];
#pragma unroll
        for (int i = 0; i < 20; ++i) {
            rowptr[base + i] = run;
            rowstart[base + i] = run;
            run += ld[i];
        }
    }
    if (t == 1023) rowptr[N_NODES] = sums[1023];
}

// ---------------- CSR fill ----------------
__global__ void k_fill(const int* __restrict__ src, const int* __restrict__ dst,
                       const float* __restrict__ dinv, int* __restrict__ rowstart,
                       int2* __restrict__ csr) {
    int e = blockIdx.x * blockDim.x + threadIdx.x;
    if (e >= N_EDGES) return;
    int s = src[e], d = dst[e];
    int pos = atomicAdd(&rowstart[d], 1);
    csr[pos] = make_int2(s, __float_as_int(dinv[s] * dinv[d]));
}

// ---------------- W2..W5 -> swizzled LDS-image panels ----------------
__global__ void k_wprep4(const float* __restrict__ W2, const float* __restrict__ W3,
                         const float* __restrict__ W4, const float* __restrict__ W5,
                         char* __restrict__ wt) {
    int lid = blockIdx.x >> 8;                       // 0..3
    int idx = (blockIdx.x & 255) * 256 + threadIdx.x;
    const float* W = lid == 0 ? W2 : lid == 1 ? W3 : lid == 2 ? W4 : W5;
    int k = idx & 255, n = idx >> 8;
    float a = W[k * 256 + n];
    unsigned u = __float_as_uint(a);
    ushort hi = (ushort)(u >> 16);
    float hif = __uint_as_float(u & 0xffff0000u);
    ushort lo = (ushort)(__float_as_uint(a - hif) >> 16);
    int half = n >> 7, colL = n & 127, slab = k >> 3, e = k & 7;
    size_t base = ((size_t)lid * 2 + half) * PANEL_BYTES;
    size_t soff = (size_t)slab * 2048 + ((colL * 16 + slab * 32) & 2047) + e * 2;
    *(ushort*)(wt + base + soff) = hi;
    *(ushort*)(wt + base + TABLE_BYTES + soff) = lo;
}

// ---------------- layer 1: aggregate raw 3-dim features (agg is linear!) ----------------
// z[i] = dinv_i^2 * x[i] + sum_e w_e * x[src_e]   (12B gathers instead of 1KB)
__global__ void k_aggx(const float* __restrict__ x, const float* __restrict__ dinv,
                       const int* __restrict__ rowptr, const int2* __restrict__ csr,
                       float* __restrict__ z) {
    int i = blockIdx.x * blockDim.x + threadIdx.x;
    if (i >= N_NODES) return;
    float di = dinv[i];
    float w0 = di * di;
    float a0 = w0 * x[i * 3], a1 = w0 * x[i * 3 + 1], a2 = w0 * x[i * 3 + 2];
    float c0 = 0.f, c1 = 0.f, c2 = 0.f;
    int k = rowptr[i], end = rowptr[i + 1];
    for (; k + 1 < end; k += 2) {
        int2 e0 = csr[k], e1 = csr[k + 1];
        float we0 = __int_as_float(e0.y), we1 = __int_as_float(e1.y);
        const float* xs0 = x + (size_t)e0.x * 3;
        const float* xs1 = x + (size_t)e1.x * 3;
        a0 = fmaf(xs0[0], we0, a0);  c0 = fmaf(xs1[0], we1, c0);
        a1 = fmaf(xs0[1], we0, a1);  c1 = fmaf(xs1[1], we1, c1);
        a2 = fmaf(xs0[2], we0, a2);  c2 = fmaf(xs1[2], we1, c2);
    }
    if (k < end) {
        int2 e0 = csr[k];
        float we0 = __int_as_float(e0.y);
        const float* xs0 = x + (size_t)e0.x * 3;
        a0 = fmaf(xs0[0], we0, a0);
        a1 = fmaf(xs0[1], we0, a1);
        a2 = fmaf(xs0[2], we0, a2);
    }
    z[i * 3 + 0] = a0 + c0;
    z[i * 3 + 1] = a1 + c1;
    z[i * 3 + 2] = a2 + c2;
}

// ---------------- layer 1: h1 = relu(z @ W1 + b1) -> hi/lo split ----------------
__global__ void k_h1(const float* __restrict__ z, const float* __restrict__ W1,
                     const float* __restrict__ b1,
                     ushort* __restrict__ out_hi, ushort* __restrict__ out_lo) {
    int i = blockIdx.x;
    int j = threadIdx.x;
    float z0 = z[i * 3], z1 = z[i * 3 + 1], z2 = z[i * 3 + 2];
    float v = fmaf(z0, W1[j], fmaf(z1, W1[256 + j], fmaf(z2, W1[512 + j], b1[j])));
    v = fmaxf(v, 0.0f);
    unsigned u = __float_as_uint(v);
    ushort hi = (ushort)(u >> 16);
    float hif = __uint_as_float(u & 0xffff0000u);
    ushort lo = (ushort)(__float_as_uint(v - hif) >> 16);
    out_hi[(size_t)i * HIDDEN + j] = hi;
    out_lo[(size_t)i * HIDDEN + j] = lo;
}

// ---------------- gather aggregation, 4-deep ILP, fused relu + bf16 split ----------------
__global__ void k_csr_agg(const float* __restrict__ h, const float* __restrict__ dinv,
                          const int* __restrict__ rowptr, const int2* __restrict__ csr,
                          const float* __restrict__ b,
                          ushort* __restrict__ out_hi, ushort* __restrict__ out_lo) {
    int node = blockIdx.x * 4 + (threadIdx.x >> 6);
    if (node >= N_NODES) return;
    int lane = threadIdx.x & 63;
    int beg = rowptr[node], end = rowptr[node + 1];
    float di = dinv[node];
    float w0 = di * di;
    float4 bv = *reinterpret_cast<const float4*>(b + lane * 4);
    float4 hv = *reinterpret_cast<const float4*>(h + (size_t)node * HIDDEN + lane * 4);
    float4 A0, A1 = {0,0,0,0}, A2 = {0,0,0,0}, A3 = {0,0,0,0};
    A0.x = fmaf(hv.x, w0, bv.x);
    A0.y = fmaf(hv.y, w0, bv.y);
    A0.z = fmaf(hv.z, w0, bv.z);
    A0.w = fmaf(hv.w, w0, bv.w);
    int k = beg;
    for (; k + 3 < end; k += 4) {
        int2 e0 = csr[k], e1 = csr[k + 1], e2 = csr[k + 2], e3 = csr[k + 3];
        float we0 = __int_as_float(e0.y), we1 = __int_as_float(e1.y);
        float we2 = __int_as_float(e2.y), we3 = __int_as_float(e3.y);
        float4 v0 = *reinterpret_cast<const float4*>(h + (size_t)e0.x * HIDDEN + lane * 4);
        float4 v1 = *reinterpret_cast<const float4*>(h + (size_t)e1.x * HIDDEN + lane * 4);
        float4 v2 = *reinterpret_cast<const float4*>(h + (size_t)e2.x * HIDDEN + lane * 4);
        float4 v3 = *reinterpret_cast<const float4*>(h + (size_t)e3.x * HIDDEN + lane * 4);
        A0.x = fmaf(v0.x, we0, A0.x);  A1.x = fmaf(v1.x, we1, A1.x);
        A0.y = fmaf(v0.y, we0, A0.y);  A1.y = fmaf(v1.y, we1, A1.y);
        A0.z = fmaf(v0.z, we0, A0.z);  A1.z = fmaf(v1.z, we1, A1.z);
        A0.w = fmaf(v0.w, we0, A0.w);  A1.w = fmaf(v1.w, we1, A1.w);
        A2.x = fmaf(v2.x, we2, A2.x);  A3.x = fmaf(v3.x, we3, A3.x);
        A2.y = fmaf(v2.y, we2, A2.y);  A3.y = fmaf(v3.y, we3, A3.y);
        A2.z = fmaf(v2.z, we2, A2.z);  A3.z = fmaf(v3.z, we3, A3.z);
        A2.w = fmaf(v2.w, we2, A2.w);  A3.w = fmaf(v3.w, we3, A3.w);
    }
    for (; k < end; ++k) {
        int2 e0 = csr[k];
        float we0 = __int_as_float(e0.y);
        float4 v0 = *reinterpret_cast<const float4*>(h + (size_t)e0.x * HIDDEN + lane * 4);
        A0.x = fmaf(v0.x, we0, A0.x);
        A0.y = fmaf(v0.y, we0, A0.y);
        A0.z = fmaf(v0.z, we0, A0.z);
        A0.w = fmaf(v0.w, we0, A0.w);
    }
    float4 acc;
    acc.x = (A0.x + A1.x) + (A2.x + A3.x);
    acc.y = (A0.y + A1.y) + (A2.y + A3.y);
    acc.z = (A0.z + A1.z) + (A2.z + A3.z);
    acc.w = (A0.w + A1.w) + (A2.w + A3.w);
    float rv[4] = {fmaxf(acc.x, 0.f), fmaxf(acc.y, 0.f), fmaxf(acc.z, 0.f), fmaxf(acc.w, 0.f)};
    us4 hvv, lvv;
#pragma unroll
    for (int j = 0; j < 4; ++j) {
        unsigned u = __float_as_uint(rv[j]);
        hvv[j] = (ushort)(u >> 16);
        float hif = __uint_as_float(u & 0xffff0000u);
        lvv[j] = (ushort)(__float_as_uint(rv[j] - hif) >> 16);
    }
    *reinterpret_cast<us4*>(out_hi + (size_t)node * HIDDEN + lane * 4) = hvv;
    *reinterpret_cast<us4*>(out_lo + (size_t)node * HIDDEN + lane * 4) = lvv;
}

// ---------------- MFMA split-bf16 GEMM with LDS-staged B panel ----------------
__global__ __launch_bounds__(512) void k_gemm_mfma(const ushort* __restrict__ a_hi,
                                                   const ushort* __restrict__ a_lo,
                                                   const char* __restrict__ wpanels,
                                                   float* __restrict__ out) {
    extern __shared__ char smem[];
    int bx = blockIdx.x;
    int half = bx & 1;
    int mtile = bx >> 1;
    const char* gsrc = wpanels + (size_t)half * PANEL_BYTES;
    int tid = threadIdx.x;
#pragma unroll
    for (int it = 0; it < 16; ++it) {
        int o = it * 8192 + tid * 16;
        *reinterpret_cast<float4*>(smem + o) = *reinterpret_cast<const float4*>(gsrc + o);
    }
    __syncthreads();

    int w = tid >> 6, l = tid & 63;
    int lr = l & 15, kg = l >> 4;
    int wm = w >> 2, wn = w & 3;          // 2M x 4N
    int row0 = mtile * 64 + wm * 32;
    int colL0 = wn * 32;

    const ushort* aph = a_hi + (size_t)(row0 + lr) * HIDDEN + kg * 8;
    const ushort* apl = a_lo + (size_t)(row0 + lr) * HIDDEN + kg * 8;

    f32x4 acc[2][2] = {};
#pragma unroll
    for (int t = 0; t < 8; ++t) {
        int kb = t * 32;
        short8v ah0 = *reinterpret_cast<const short8v*>(aph + kb);
        short8v ah1 = *reinterpret_cast<const short8v*>(aph + 16 * HIDDEN + kb);
        short8v al0 = *reinterpret_cast<const short8v*>(apl + kb);
        short8v al1 = *reinterpret_cast<const short8v*>(apl + 16 * HIDDEN + kb);
        int slab = t * 4 + kg;
        int sbase = slab * 2048;
        int rot = slab * 32;
#pragma unroll
        for (int cf = 0; cf < 2; ++cf) {
            int colL = colL0 + cf * 16 + lr;
            int off = sbase + ((colL * 16 + rot) & 2047);
            short8v bh = *reinterpret_cast<const short8v*>(smem + off);
            short8v bl = *reinterpret_cast<const short8v*>(smem + TABLE_BYTES + off);
            acc[0][cf] = __builtin_amdgcn_mfma_f32_16x16x32_bf16(ah0, bh, acc[0][cf], 0, 0, 0);
            acc[1][cf] = __builtin_amdgcn_mfma_f32_16x16x32_bf16(ah1, bh, acc[1][cf], 0, 0, 0);
            acc[0][cf] = __builtin_amdgcn_mfma_f32_16x16x32_bf16(al0, bh, acc[0][cf], 0, 0, 0);
            acc[1][cf] = __builtin_amdgcn_mfma_f32_16x16x32_bf16(al1, bh, acc[1][cf], 0, 0, 0);
            acc[0][cf] = __builtin_amdgcn_mfma_f32_16x16x32_bf16(ah0, bl, acc[0][cf], 0, 0, 0);
            acc[1][cf] = __builtin_amdgcn_mfma_f32_16x16x32_bf16(ah1, bl, acc[1][cf], 0, 0, 0);
        }
    }
    int gcol = half * 128 + colL0 + lr;
#pragma unroll
    for (int rf = 0; rf < 2; ++rf) {
        float* orow = out + (size_t)(row0 + rf * 16 + kg * 4) * HIDDEN + gcol;
#pragma unroll
        for (int r = 0; r < 4; ++r)
#pragma unroll
            for (int cf = 0; cf < 2; ++cf)
                orow[(size_t)r * HIDDEN + cf * 16] = acc[rf][cf][r];
    }
}

// ---------------- pooling from hi/lo (already relu'd) ----------------
__global__ void k_pool(const ushort* __restrict__ hi, const ushort* __restrict__ lo,
                       const int* __restrict__ batch, float* __restrict__ pooled) {
    int base = blockIdx.x * 32;
    int j = threadIdx.x;
    float acc = 0.0f;
    int cur = batch[base];
    for (int r = 0; r < 32; ++r) {
        int i = base + r;
        int bg = batch[i];
        if (bg != cur) {
            atomicAdd(&pooled[cur * HIDDEN + j], acc);
            acc = 0.0f;
            cur = bg;
        }
        size_t off = (size_t)i * HIDDEN + j;
        float v = __uint_as_float((unsigned)hi[off] << 16) +
                  __uint_as_float((unsigned)lo[off] << 16);
        acc += v;
    }
    atomicAdd(&pooled[cur * HIDDEN + j], acc);
}

// ---------------- final linear ----------------
__global__ void k_final(const float* __restrict__ pooled, const float* __restrict__ Wlin,
                        const float* __restrict__ blin, float* __restrict__ out) {
    int t = threadIdx.x; // 0..127
    int g = t >> 1, o = t & 1;
    float s = blin[o];
    for (int k = 0; k < HIDDEN; ++k) s += pooled[g * HIDDEN + k] * Wlin[k * OUT_DIM + o];
    out[g * OUT_DIM + o] = s;
}

extern "C" void kernel_launch(void* const* d_in, const int* in_sizes, int n_in,
                              void* d_out, int out_size, void* d_ws, size_t ws_size,
                              hipStream_t stream) {
    const float* x     = (const float*)d_in[0];
    const int*   esrc  = (const int*)d_in[1];
    const int*   edst  = esrc + N_EDGES;
    const int*   batch = (const int*)d_in[2];
    const float* W1 = (const float*)d_in[3];
    const float* b1 = (const float*)d_in[4];
    const float* W2 = (const float*)d_in[5];
    const float* b2 = (const float*)d_in[6];
    const float* W3 = (const float*)d_in[7];
    const float* b3 = (const float*)d_in[8];
    const float* W4 = (const float*)d_in[9];
    const float* b4 = (const float*)d_in[10];
    const float* W5 = (const float*)d_in[11];
    const float* b5 = (const float*)d_in[12];
    const float* Wlin = (const float*)d_in[13];
    const float* blin = (const float*)d_in[14];
    float* out = (float*)d_out;

    char* ws = (char*)d_ws;
    size_t off = 0;
    auto alloc = [&](size_t bytes) { size_t o = off; off += (bytes + 255) & ~size_t(255); return (void*)(ws + o); };

    int*    degi     = (int*)alloc(N_NODES * 4);
    float*  dinv     = (float*)alloc(N_NODES * 4);
    int*    rowptr   = (int*)alloc((N_NODES + 1) * 4);
    int*    rowstart = (int*)alloc(N_NODES * 4);
    int2*   csr      = (int2*)alloc((size_t)N_EDGES * 8);
    float*  hA       = (float*)alloc((size_t)N_PAD * HIDDEN * 4);
    ushort* hb_hi    = (ushort*)alloc((size_t)N_PAD * HIDDEN * 2);
    ushort* hb_lo    = (ushort*)alloc((size_t)N_PAD * HIDDEN * 2);
    float*  pooled   = (float*)alloc(N_GRAPHS * HIDDEN * 4);
    char*   wt       = (char*)alloc((size_t)4 * 2 * PANEL_BYTES);
    float*  z        = (float*)alloc((size_t)N_NODES * 3 * 4);

    hipMemsetAsync(degi, 0, N_NODES * 4, stream);
    hipMemsetAsync(pooled, 0, N_GRAPHS * HIDDEN * 4, stream);

    k_degree<<<(N_EDGES + 255) / 256, 256, 0, stream>>>(edst, degi);
    k_dinv<<<(N_NODES + 255) / 256, 256, 0, stream>>>(degi, dinv);
    k_scan<<<1, 1024, 0, stream>>>(degi, rowptr, rowstart);
    k_fill<<<(N_EDGES + 255) / 256, 256, 0, stream>>>(esrc, edst, dinv, rowstart, csr);
    k_wprep4<<<1024, 256, 0, stream>>>(W2, W3, W4, W5, wt);

    const float* bs[5] = {b1, b2, b3, b4, b5};

    // layer 1 (reassociated): z = A*x, h1 = relu(z @ W1 + b1)
    k_aggx<<<(N_NODES + 255) / 256, 256, 0, stream>>>(x, dinv, rowptr, csr, z);
    k_h1<<<N_NODES, HIDDEN, 0, stream>>>(z, W1, b1, hb_hi, hb_lo);

    // layers 2..5
    for (int l = 1; l < 5; ++l) {
        k_gemm_mfma<<<(N_PAD / 64) * 2, 512, PANEL_BYTES, stream>>>(
            hb_hi, hb_lo, wt + (size_t)(l - 1) * 2 * PANEL_BYTES, hA);
        k_csr_agg<<<N_NODES / 4, 256, 0, stream>>>(hA, dinv, rowptr, csr, bs[l], hb_hi, hb_lo);
    }

    k_pool<<<N_NODES / 32, HIDDEN, 0, stream>>>(hb_hi, hb_lo, batch, pooled);
    k_final<<<1, 128, 0, stream>>>(pooled, Wlin, blin, out);
}